// Round 3
// baseline (222.874 us; speedup 1.0000x reference)
//
#include <hip/hip_runtime.h>

// R1 post-mortem: gather 89us (74MB WRITE amplification, 110MB FETCH), plus
// ~124us spread over 6 serial preprocessing dispatches. R2: 3 dispatches total
// (fused prep, single-block LDS scan+fill, gather). Gather loads collapse to
// one b128 bf16 feat load + 2 uniform float4 probs loads per entry; output
// lines are XCD-grouped (blockIdx%8) so the 32 bins sharing an out cache line
// merge in one L2.

constexpr int D = 40, H = 32, W = 88, HW = H * W;       // 2816
constexpr int C = 128, NCAM = 6;
constexpr int BEV = 125, NBINS = BEV * BEV;             // 15625
constexpr int NPTS = D * HW;                            // 112640 = 110*1024
constexpr int NCOLS = NCAM * HW;                        // 16896

// feat_p: [hw][c][8] bf16 (cams 0-5 + 2 zero pads) = 16B per (hw,c)
// probs_t: [(d<<12)|hw][8] fp32 (cams 0-5 + 2 don't-care pads) = 32B per point

typedef __attribute__((ext_vector_type(8))) unsigned short us8;

__device__ __forceinline__ unsigned short f2bf(float x) {   // RNE
    unsigned u = __float_as_uint(x);
    return (unsigned short)((u + 0x7FFF + ((u >> 16) & 1)) >> 16);
}
__device__ __forceinline__ float b2f(unsigned short u) {
    return __uint_as_float(((unsigned)u) << 16);
}

// Exact IEEE fp32 replication of _voxel_indices (verified R1).
__device__ __forceinline__ int bin_of(int pt) {
    int d  = pt / HW;
    int hw = pt - d * HW;
    int h  = hw / W;
    int w  = hw - h * W;
    float dep = (float)(d + 2);
    float gx = __fadd_rn(__fmul_rn(__fdiv_rn((float)w * dep, 3567.0f), 100.0f), -50.0f);
    float gy = __fadd_rn(__fmul_rn(__fdiv_rn((float)h * dep, 1271.0f), 100.0f), -50.0f);
    int ix = (int)__fdiv_rn(__fadd_rn(gx, 50.0f), 0.8f);
    int iy = (int)__fdiv_rn(__fadd_rn(gy, 50.0f), 0.8f);
    bool valid = (ix >= 0) & (ix < BEV) & (iy >= 0) & (iy < BEV);
    return valid ? (iy * BEV + ix) : -1;
}

// ---------------------------------------------------------------- K1: fused prep
// blocks 0..351   : pack feat -> bf16 [hw][c][8]   (32hw x 32c tile, all cams)
// blocks 352..461 : bin table + histogram (1 point per thread, 110*1024 = NPTS)
// blocks 462..478 : softmax -> probs_t [(d<<12)|hw][8]
constexpr int PACK_BLOCKS = (HW / 32) * (C / 32);   // 352
constexpr int HIST_BLOCKS = NPTS / 1024;            // 110
constexpr int SMAX_BLOCKS = (NCOLS + 1023) / 1024;  // 17

__global__ void __launch_bounds__(1024) prep_kernel(
        const float* __restrict__ feat,     // [NCAM][C][HW]
        const float* __restrict__ logits,   // [NCAM][D][HW]
        float* __restrict__ probs_t,
        unsigned short* __restrict__ feat_p,
        int* __restrict__ tab,
        int* __restrict__ cnt) {
    int b = blockIdx.x, tid = threadIdx.x;

    if (b < PACK_BLOCKS) {
        __shared__ float tile[NCAM * 32 * 33];
        int hw0 = (b % (HW / 32)) * 32;
        int c0  = (b / (HW / 32)) * 32;
        int cq = tid >> 5, hwL = tid & 31;          // load: 1 elem per cam
#pragma unroll
        for (int n = 0; n < NCAM; ++n)
            tile[(n * 32 + cq) * 33 + hwL] =
                feat[((size_t)(n * C + c0 + cq)) * HW + hw0 + hwL];
        __syncthreads();
        int c = tid & 31, hl = tid >> 5;            // store: 1 (hw,c) per thread
        us8 v;
#pragma unroll
        for (int n = 0; n < NCAM; ++n)
            v[n] = f2bf(tile[(n * 32 + c) * 33 + hl]);
        v[6] = 0; v[7] = 0;
        *(us8*)(feat_p + ((size_t)(hw0 + hl) * C + (c0 + c)) * 8) = v;

    } else if (b < PACK_BLOCKS + HIST_BLOCKS) {
        int pt = (b - PACK_BLOCKS) * 1024 + tid;    // < NPTS exactly
        int bin = bin_of(pt);
        tab[pt] = bin;
        if (bin >= 0) atomicAdd(&cnt[bin], 1);

    } else {
        int col = (b - PACK_BLOCKS - HIST_BLOCKS) * 1024 + tid;
        if (col >= NCOLS) return;
        int n  = col / HW;
        int hw = col - n * HW;
        const float* src = logits + ((size_t)n * D) * HW + hw;
        float v[D];
        float m = -3.402823466e+38f;
#pragma unroll
        for (int d = 0; d < D; ++d) {
            v[d] = src[(size_t)d * HW];
            m = fmaxf(m, v[d]);
        }
        float s = 0.f;
#pragma unroll
        for (int d = 0; d < D; ++d) { v[d] = expf(v[d] - m); s += v[d]; }
        float inv = 1.0f / s;
#pragma unroll
        for (int d = 0; d < D; ++d)
            probs_t[(size_t)((d << 12) | hw) * 8 + n] = v[d] * inv;
    }
}

// ---------------------------------------------------------------- K2: scan + fill
// One block, cursors in LDS (62.5 KB). Wave-shfl hierarchical scan.
__global__ void __launch_bounds__(1024) scanfill_kernel(
        const int* __restrict__ cnt, const int* __restrict__ tab,
        int* __restrict__ offsets, int* __restrict__ entries) {
    __shared__ unsigned int curs[NBINS];
    __shared__ unsigned int wsum[16];
    int t = threadIdx.x, lane = t & 63, wid = t >> 6;
    int base = t * 16;
    unsigned int cl[16], s = 0;
#pragma unroll
    for (int i = 0; i < 16; ++i) {
        int idx = base + i;
        unsigned v = (idx < NBINS) ? (unsigned)cnt[idx] : 0u;
        cl[i] = v; s += v;
    }
    unsigned own = s;
    for (int o = 1; o < 64; o <<= 1) {              // inclusive wave scan
        unsigned v = (unsigned)__shfl_up((int)s, o);
        if (lane >= o) s += v;
    }
    if (lane == 63) wsum[wid] = s;
    __syncthreads();
    unsigned run = s - own;                          // exclusive within wave
    for (int i = 0; i < wid; ++i) run += wsum[i];
#pragma unroll
    for (int i = 0; i < 16; ++i) {
        int idx = base + i;
        if (idx < NBINS) { offsets[idx] = run; curs[idx] = run; run += cl[i]; }
    }
    if (t == 1023) offsets[NBINS] = run;             // grand total
    __syncthreads();
    for (int pt = t; pt < NPTS; pt += 1024) {
        int bin = tab[pt];
        if (bin < 0) continue;
        unsigned pos = atomicAdd(&curs[bin], 1u);
        int d = pt / HW, hw = pt - d * HW;
        entries[pos] = (d << 12) | hw;               // == probs_t index
    }
}

// ---------------------------------------------------------------- K3: gather
// Persistent blocks, XCD-grouped bins: all 32 bins of an out cache line are
// handled by blocks with the same blockIdx%8 -> writes merge in one L2.
constexpr int GB = 2048;                             // gather blocks
__global__ void __launch_bounds__(128) gather_kernel(
        const unsigned short* __restrict__ feat_p,
        const float* __restrict__ probs_t,
        const int* __restrict__ entries,
        const int* __restrict__ offsets,
        float* __restrict__ out) {                   // [C][NBINS]
    int c = threadIdx.x;
    int x = blockIdx.x & 7, k = blockIdx.x >> 3;
    for (int f = k; f < 62 * 32; f += GB / 8) {
        int g = x + ((f >> 5) << 3);                 // group of 32 bins, g%8==x
        int bin = (g << 5) | (f & 31);
        if (bin >= NBINS) continue;
        int beg = offsets[bin], end = offsets[bin + 1];
        float acc = 0.f;
        int e = beg;
        for (; e + 2 <= end; e += 2) {               // 2-way unroll for MLP
            int pk0 = entries[e], pk1 = entries[e + 1];
            us8 f0 = *(const us8*)(feat_p + (size_t)(pk0 & 4095) * (C * 8) + c * 8);
            us8 f1 = *(const us8*)(feat_p + (size_t)(pk1 & 4095) * (C * 8) + c * 8);
            const float* p0 = probs_t + (size_t)pk0 * 8;
            const float* p1 = probs_t + (size_t)pk1 * 8;
            float a0 = p0[0] * b2f(f0[0]) + p0[1] * b2f(f0[1]) + p0[2] * b2f(f0[2])
                     + p0[3] * b2f(f0[3]) + p0[4] * b2f(f0[4]) + p0[5] * b2f(f0[5]);
            float a1 = p1[0] * b2f(f1[0]) + p1[1] * b2f(f1[1]) + p1[2] * b2f(f1[2])
                     + p1[3] * b2f(f1[3]) + p1[4] * b2f(f1[4]) + p1[5] * b2f(f1[5]);
            acc += a0 + a1;
        }
        if (e < end) {
            int pk = entries[e];
            us8 fv = *(const us8*)(feat_p + (size_t)(pk & 4095) * (C * 8) + c * 8);
            const float* p = probs_t + (size_t)pk * 8;
            acc += p[0] * b2f(fv[0]) + p[1] * b2f(fv[1]) + p[2] * b2f(fv[2])
                 + p[3] * b2f(fv[3]) + p[4] * b2f(fv[4]) + p[5] * b2f(fv[5]);
        }
        out[(size_t)c * NBINS + bin] = acc;
    }
}

// ---------------------------------------------------------------- launch
extern "C" void kernel_launch(void* const* d_in, const int* in_sizes, int n_in,
                              void* d_out, int out_size, void* d_ws, size_t ws_size,
                              hipStream_t stream) {
    const float* img_feat     = (const float*)d_in[0];
    const float* depth_logits = (const float*)d_in[1];
    float* out = (float*)d_out;

    char* p = (char*)d_ws;
    float*          probs_t = (float*)p;          p += (size_t)D * 4096 * 8 * 4;  // 5.24 MB
    unsigned short* feat_p  = (unsigned short*)p; p += (size_t)HW * C * 8 * 2;    // 5.77 MB
    int*            tab     = (int*)p;            p += (size_t)NPTS * 4;          // 450 KB
    int*            cnt     = (int*)p;            p += (size_t)NBINS * 4;
    int*            offsets = (int*)p;            p += (size_t)(NBINS + 1) * 4;
    int*            entries = (int*)p;            p += (size_t)NPTS * 4;

    hipMemsetAsync(cnt, 0, (size_t)NBINS * 4, stream);
    prep_kernel<<<PACK_BLOCKS + HIST_BLOCKS + SMAX_BLOCKS, 1024, 0, stream>>>(
        img_feat, depth_logits, probs_t, feat_p, tab, cnt);
    scanfill_kernel<<<1, 1024, 0, stream>>>(cnt, tab, offsets, entries);
    gather_kernel<<<GB, 128, 0, stream>>>(feat_p, probs_t, entries, offsets, out);
}

// Round 4
// 205.938 us; speedup vs baseline: 1.0822x; 1.0822x over previous
//
#include <hip/hip_runtime.h>

// R2 post-mortem: single-block scanfill = 65us (1 CU serialization, LDS-atomic
// cursor conflicts). R3: CSR build is separable/closed-form -> tables (1 tiny
// block) + counts in prep + scan-only block + ATOMIC-FREE parallel fill.
// Gather rebalanced by entry-chunks (64/block) instead of bins: interior bins
// plain-store, boundary bins atomicAdd (~2/chunk). Out memset once.

constexpr int D = 40, H = 32, W = 88, HW = H * W;       // 2816
constexpr int C = 128, NCAM = 6;
constexpr int BEV = 125, NBINS = BEV * BEV;             // 15625
constexpr int NPTS = D * HW;                            // 112640
constexpr int NCOLS = NCAM * HW;                        // 16896
constexpr int TSZ = D * BEV;                            // 5000 per table

typedef __attribute__((ext_vector_type(8))) unsigned short us8;
typedef __attribute__((ext_vector_type(4))) float f4;

__device__ __forceinline__ unsigned short f2bf(float x) {   // RNE
    unsigned u = __float_as_uint(x);
    return (unsigned short)((u + 0x7FFF + ((u >> 16) & 1)) >> 16);
}
__device__ __forceinline__ float b2f(unsigned short u) {
    return __uint_as_float(((unsigned)u) << 16);
}

// Exact IEEE fp32 replication of _voxel_indices (verified R1/R2).
// ix monotone non-decreasing in w (gx strictly increasing); never negative.
__device__ __forceinline__ int ix_of(int w, float dep) {
    float gx = __fadd_rn(__fmul_rn(__fdiv_rn((float)w * dep, 3567.0f), 100.0f), -50.0f);
    return (int)__fdiv_rn(__fadd_rn(gx, 50.0f), 0.8f);
}
__device__ __forceinline__ int iy_of(int h, float dep) {
    float gy = __fadd_rn(__fmul_rn(__fdiv_rn((float)h * dep, 1271.0f), 100.0f), -50.0f);
    return (int)__fdiv_rn(__fadd_rn(gy, 50.0f), 0.8f);
}

// ---------------------------------------------------------------- K1: tables
// tabs = [xcnt | xfirst | ycnt | yfirst], each D*BEV ints. One small block;
// sequential per (d,axis) thread over <=88 items, built in LDS.
__global__ void __launch_bounds__(128) tables_kernel(int* __restrict__ tabs) {
    __shared__ short xc[TSZ], xf[TSZ], yc[TSZ], yf[TSZ];
    int t = threadIdx.x;
    for (int i = t; i < TSZ; i += 128) { xc[i] = 0; yc[i] = 0; xf[i] = 0; yf[i] = 0; }
    __syncthreads();
    if (t < D) {                                    // x-axis for depth t
        float dep = (float)(t + 2);
        for (int w = 0; w < W; ++w) {
            int ix = ix_of(w, dep);
            if (ix < BEV) { if (xc[t * BEV + ix] == 0) xf[t * BEV + ix] = (short)w; xc[t * BEV + ix]++; }
        }
    } else if (t >= 64 && t < 64 + D) {             // y-axis (separate wave)
        int d = t - 64;
        float dep = (float)(d + 2);
        for (int h = 0; h < H; ++h) {
            int iy = iy_of(h, dep);
            if (iy < BEV) { if (yc[d * BEV + iy] == 0) yf[d * BEV + iy] = (short)h; yc[d * BEV + iy]++; }
        }
    }
    __syncthreads();
    for (int i = t; i < TSZ; i += 128) {
        tabs[i]           = xc[i];
        tabs[TSZ + i]     = xf[i];
        tabs[2 * TSZ + i] = yc[i];
        tabs[3 * TSZ + i] = yf[i];
    }
}

// ---------------------------------------------------------------- K2: prep
// blocks [0,352)      : pack feat -> bf16 [hw][c][8]
// blocks [352,369)    : softmax -> probs_t [(d<<12)|hw][8] fp32
// blocks [369,385)    : cnt[bin] = sum_d xcnt[d][ix]*ycnt[d][iy]  (no atomics)
constexpr int PACK_BLOCKS = (HW / 32) * (C / 32);   // 352
constexpr int SMAX_BLOCKS = (NCOLS + 1023) / 1024;  // 17
constexpr int CNT_BLOCKS  = (NBINS + 1023) / 1024;  // 16

__global__ void __launch_bounds__(1024) prep_kernel(
        const float* __restrict__ feat,     // [NCAM][C][HW]
        const float* __restrict__ logits,   // [NCAM][D][HW]
        const int*   __restrict__ tabs,
        float* __restrict__ probs_t,
        unsigned short* __restrict__ feat_p,
        int* __restrict__ cnt) {
    int b = blockIdx.x, tid = threadIdx.x;

    if (b < PACK_BLOCKS) {
        __shared__ float tile[NCAM * 32 * 33];
        int hw0 = (b % (HW / 32)) * 32;
        int c0  = (b / (HW / 32)) * 32;
        int cq = tid >> 5, hwL = tid & 31;
#pragma unroll
        for (int n = 0; n < NCAM; ++n)
            tile[(n * 32 + cq) * 33 + hwL] =
                feat[((size_t)(n * C + c0 + cq)) * HW + hw0 + hwL];
        __syncthreads();
        int c = tid & 31, hl = tid >> 5;
        us8 v;
#pragma unroll
        for (int n = 0; n < NCAM; ++n)
            v[n] = f2bf(tile[(n * 32 + c) * 33 + hl]);
        v[6] = 0; v[7] = 0;
        *(us8*)(feat_p + ((size_t)(hw0 + hl) * C + (c0 + c)) * 8) = v;

    } else if (b < PACK_BLOCKS + SMAX_BLOCKS) {
        int col = (b - PACK_BLOCKS) * 1024 + tid;
        if (col >= NCOLS) return;
        int n  = col / HW;
        int hw = col - n * HW;
        const float* src = logits + ((size_t)n * D) * HW + hw;
        float v[D];
        float m = -3.402823466e+38f;
#pragma unroll
        for (int d = 0; d < D; ++d) {
            v[d] = src[(size_t)d * HW];
            m = fmaxf(m, v[d]);
        }
        float s = 0.f;
#pragma unroll
        for (int d = 0; d < D; ++d) { v[d] = expf(v[d] - m); s += v[d]; }
        float inv = 1.0f / s;
#pragma unroll
        for (int d = 0; d < D; ++d)
            probs_t[(size_t)((d << 12) | hw) * 8 + n] = v[d] * inv;

    } else {
        int bin = (b - PACK_BLOCKS - SMAX_BLOCKS) * 1024 + tid;
        if (bin >= NBINS) return;
        int iy = bin / BEV, ix = bin - iy * BEV;
        const int* xc = tabs;
        const int* yc = tabs + 2 * TSZ;
        int s = 0;
#pragma unroll 8
        for (int d = 0; d < D; ++d)
            s += xc[d * BEV + ix] * yc[d * BEV + iy];
        cnt[bin] = s;
    }
}

// ---------------------------------------------------------------- K3: scan
// Single block; 16 bins/thread + shfl hierarchical scan (verified R2).
__global__ void __launch_bounds__(1024) scan_kernel(
        const int* __restrict__ cnt, int* __restrict__ offsets) {
    __shared__ unsigned wsum[16];
    int t = threadIdx.x, lane = t & 63, wid = t >> 6;
    int base = t * 16;
    unsigned cl[16], s = 0;
#pragma unroll
    for (int i = 0; i < 16; ++i) {
        int idx = base + i;
        unsigned v = (idx < NBINS) ? (unsigned)cnt[idx] : 0u;
        cl[i] = v; s += v;
    }
    unsigned own = s;
    for (int o = 1; o < 64; o <<= 1) {
        unsigned v = (unsigned)__shfl_up((int)s, o);
        if (lane >= o) s += v;
    }
    if (lane == 63) wsum[wid] = s;
    __syncthreads();
    unsigned run = s - own;
    for (int i = 0; i < wid; ++i) run += wsum[i];
#pragma unroll
    for (int i = 0; i < 16; ++i) {
        int idx = base + i;
        if (idx < NBINS) offsets[idx] = run;
        run += cl[i];
    }
    if (t == 1023) offsets[NBINS] = run;
}

// ---------------------------------------------------------------- K4: fill
// Atomic-free: rank of (d,h,w) within its bin is closed-form from tables.
// Entry = (bin<<18)|(d<<12)|hw ; entries sorted by (bin, d, h, w).
__global__ void __launch_bounds__(256) fill_kernel(
        const int* __restrict__ tabs, const int* __restrict__ offsets,
        int* __restrict__ entries) {
    int pt = blockIdx.x * 256 + threadIdx.x;
    if (pt >= NPTS) return;
    int d = pt / HW, hw = pt - d * HW, h = hw / W, w = hw - h * W;
    float dep = (float)(d + 2);
    int ix = ix_of(w, dep), iy = iy_of(h, dep);
    if (ix >= BEV || iy >= BEV) return;
    const int* xc = tabs;
    const int* xf = tabs + TSZ;
    const int* yc = tabs + 2 * TSZ;
    const int* yf = tabs + 3 * TSZ;
    int r = 0;
    for (int dd = 0; dd < d; ++dd)                   // d is wave-uniform
        r += xc[dd * BEV + ix] * yc[dd * BEV + iy];
    r += (h - yf[d * BEV + iy]) * xc[d * BEV + ix] + (w - xf[d * BEV + ix]);
    int bin = iy * BEV + ix;
    entries[offsets[bin] + r] = ((unsigned)bin << 18) | ((unsigned)d << 12) | (unsigned)hw;
}

// ---------------------------------------------------------------- K5: gather
// Entry-balanced: block = one 64-entry chunk (bin-sorted), 128 threads = c.
// Interior bins: exactly-once plain store. Boundary bins (~2/chunk): atomicAdd
// onto pre-zeroed out. Chunk swizzle groups consecutive chunks per XCD so
// adjacent-bin out lines merge in one L2.
constexpr int CHUNK  = 64;
constexpr int NCHUNK = (NPTS + CHUNK - 1) / CHUNK;   // 1760 (>= E/CHUNK)

__global__ void __launch_bounds__(128) gather_kernel(
        const unsigned short* __restrict__ feat_p,   // [hw][c][8] bf16
        const float* __restrict__ probs_t,           // [(d<<12)|hw][8] f32
        const int*   __restrict__ entries,
        const int*   __restrict__ offsets,
        float*       __restrict__ out) {             // [C][NBINS], pre-zeroed
    int E = offsets[NBINS];
    int b = blockIdx.x;
    int chunk = (b & 7) * (NCHUNK / 8) + (b >> 3);   // XCD grouping
    int e0 = chunk * CHUNK;
    if (e0 >= E) return;
    int eend = min(e0 + CHUNK, E);
    int c = threadIdx.x;

    unsigned prevbin = (e0 > 0) ? ((unsigned)entries[e0 - 1] >> 18) : 0xFFFFFFFFu;
    unsigned nextbin = (e0 + CHUNK < E) ? ((unsigned)entries[e0 + CHUNK] >> 18) : 0xFFFFFFFFu;

    unsigned pk = (unsigned)entries[e0];
    us8 fv = *(const us8*)(feat_p + (((pk & 0xFFFu) * 128u + (unsigned)c) << 3));
    const float* pp = probs_t + ((pk & 0x3FFFFu) << 3);
    f4 pa = *(const f4*)pp, pb = *(const f4*)(pp + 4);

    float acc = 0.f;
    int curbin = -1;
    bool inside = true;
    for (int e = e0; e < eend; ++e) {
        unsigned pkn = 0; us8 fn = fv; f4 qa = pa, qb = pb;
        if (e + 1 < eend) {                          // prefetch next entry
            pkn = (unsigned)entries[e + 1];
            fn = *(const us8*)(feat_p + (((pkn & 0xFFFu) * 128u + (unsigned)c) << 3));
            const float* q = probs_t + ((pkn & 0x3FFFFu) << 3);
            qa = *(const f4*)q; qb = *(const f4*)(q + 4);
        }
        int bin = (int)(pk >> 18);                   // wave-uniform
        if (bin != curbin) {
            if (curbin >= 0) {
                if (inside) out[(size_t)c * NBINS + curbin] = acc;
                else        atomicAdd(&out[(size_t)c * NBINS + curbin], acc);
            }
            curbin = bin; acc = 0.f;
            inside = !(e == e0 && (unsigned)bin == prevbin);
        }
        acc += pa.x * b2f(fv[0]) + pa.y * b2f(fv[1]) + pa.z * b2f(fv[2])
             + pa.w * b2f(fv[3]) + pb.x * b2f(fv[4]) + pb.y * b2f(fv[5]);
        pk = pkn; fv = fn; pa = qa; pb = qb;
    }
    bool cont = (eend == e0 + CHUNK) && ((unsigned)curbin == nextbin);
    if (cont || !inside) atomicAdd(&out[(size_t)c * NBINS + curbin], acc);
    else                 out[(size_t)c * NBINS + curbin] = acc;
}

// ---------------------------------------------------------------- launch
extern "C" void kernel_launch(void* const* d_in, const int* in_sizes, int n_in,
                              void* d_out, int out_size, void* d_ws, size_t ws_size,
                              hipStream_t stream) {
    const float* img_feat     = (const float*)d_in[0];
    const float* depth_logits = (const float*)d_in[1];
    float* out = (float*)d_out;

    char* p = (char*)d_ws;
    float*          probs_t = (float*)p;          p += (size_t)D * 4096 * 8 * 4;  // 5.24 MB
    unsigned short* feat_p  = (unsigned short*)p; p += (size_t)HW * C * 8 * 2;    // 5.77 MB
    int*            tabs    = (int*)p;            p += (size_t)4 * TSZ * 4;       // 80 KB
    int*            cnt     = (int*)p;            p += (size_t)NBINS * 4;
    int*            offsets = (int*)p;            p += (size_t)(NBINS + 1) * 4;
    int*            entries = (int*)p;            p += (size_t)NPTS * 4;

    hipMemsetAsync(out, 0, (size_t)out_size * sizeof(float), stream);
    tables_kernel<<<1, 128, 0, stream>>>(tabs);
    prep_kernel<<<PACK_BLOCKS + SMAX_BLOCKS + CNT_BLOCKS, 1024, 0, stream>>>(
        img_feat, depth_logits, tabs, probs_t, feat_p, cnt);
    scan_kernel<<<1, 1024, 0, stream>>>(cnt, offsets);
    fill_kernel<<<(NPTS + 255) / 256, 256, 0, stream>>>(tabs, offsets, entries);
    gather_kernel<<<NCHUNK, 128, 0, stream>>>(feat_p, probs_t, entries, offsets, out);
}

// Round 5
// 186.527 us; speedup vs baseline: 1.1949x; 1.1041x over previous
//
#include <hip/hip_runtime.h>

// R4: TWO dispatches (R1/R3 showed ~15us/dispatch fixed overhead; non-gather
// time stuck at ~130us over 6-7 dispatches).
//  D1 mega: fill(closed-form CSR, per-block LDS prefix tables) || feat pack
//           || softmax || zero-out.
//  D2 gather: chunk=32, entries preloaded via one coalesced load + shfl
//           broadcast (kills R3's per-iter load->addr chain), batch-4 loads.

constexpr int D = 40, H = 32, W = 88, HW = H * W;       // 2816
constexpr int C = 128, NCAM = 6;
constexpr int BEV = 125, NBINS = BEV * BEV;             // 15625
constexpr int NPTS = D * HW;                            // 112640
constexpr int NCOLS = NCAM * HW;                        // 16896

typedef __attribute__((ext_vector_type(8))) unsigned short us8;
typedef __attribute__((ext_vector_type(4))) float f4;

__device__ __forceinline__ unsigned short f2bf(float x) {   // RNE
    unsigned u = __float_as_uint(x);
    return (unsigned short)((u + 0x7FFF + ((u >> 16) & 1)) >> 16);
}
__device__ __forceinline__ float b2f(unsigned short u) {
    return __uint_as_float(((unsigned)u) << 16);
}

// Exact IEEE fp32 replication of _voxel_indices (verified R1-R3).
// ix/iy monotone non-decreasing in w/h; never negative; max exactly 124.
__device__ __forceinline__ int ix_of(int w, float dep) {
    float gx = __fadd_rn(__fmul_rn(__fdiv_rn((float)w * dep, 3567.0f), 100.0f), -50.0f);
    return (int)__fdiv_rn(__fadd_rn(gx, 50.0f), 0.8f);
}
__device__ __forceinline__ int iy_of(int h, float dep) {
    float gy = __fadd_rn(__fmul_rn(__fdiv_rn((float)h * dep, 1271.0f), 100.0f), -50.0f);
    return (int)__fdiv_rn(__fadd_rn(gy, 50.0f), 0.8f);
}

// ---------------------------------------------------------------- D1: mega
// blocks [0,440)      : fill (entries via closed-form offset+rank)
// blocks [440,1848)   : pack feat -> bf16 [hw][c][8]
// blocks [1848,1914)  : softmax -> probs_t [(d<<12)|hw][8] fp32
// blocks [1914,2403)  : zero out (replaces memset dispatch)
constexpr int FILL_BLOCKS = NPTS / 256;          // 440
constexpr int PACK_BLOCKS = (C / 8) * (HW / 32); // 1408
constexpr int SMAX_BLOCKS = NCOLS / 256;         // 66
constexpr int ZERO_TOTAL  = C * NBINS / 4;       // 500000 f4
constexpr int ZERO_BLOCKS = (ZERO_TOTAL + 1023) / 1024;  // 489

__global__ void __launch_bounds__(256) mega_kernel(
        const float* __restrict__ feat,     // [NCAM][C][HW]
        const float* __restrict__ logits,   // [NCAM][D][HW]
        float* __restrict__ probs_t,
        unsigned short* __restrict__ feat_p,
        int* __restrict__ entries,
        int* __restrict__ E_global,
        float* __restrict__ out) {
    __shared__ __align__(16) char smem[21200];
    int b = blockIdx.x, t = threadIdx.x;

    if (b < FILL_BLOCKS) {
        // XPexc[d][X] = #{w: ix(w)<X} (shorts, row len 126); same for Y.
        short* XP = (short*)smem;                   // 40*126*2 = 10080 B
        short* YP = (short*)(smem + 10080);         // 10080 B
        int*   R  = (int*)(smem + 20160);           // 125*4
        int*   RP = (int*)(smem + 20660);           // 126*4   (tot 21164)

        if (t < D) {                                // x prefix table, depth t
            float dep = (float)(t + 2);
            int nextX = 0, run = 0;
            for (int w = 0; w < W; ++w) {
                int ix = ix_of(w, dep);
                if (ix <= 124) {
                    while (nextX <= ix) XP[t * 126 + nextX++] = (short)run;
                    run++;
                }
            }
            while (nextX <= 125) XP[t * 126 + nextX++] = (short)run;
        } else if (t >= 64 && t < 64 + D) {         // y prefix table
            int d = t - 64;
            float dep = (float)(d + 2);
            int nextY = 0, run = 0;
            for (int h = 0; h < H; ++h) {
                int iy = iy_of(h, dep);
                if (iy <= 124) {
                    while (nextY <= iy) YP[d * 126 + nextY++] = (short)run;
                    run++;
                }
            }
            while (nextY <= 125) YP[d * 126 + nextY++] = (short)run;
        }
        __syncthreads();
        if (t < 125) {                              // row totals
            int s = 0;
            for (int d = 0; d < D; ++d)
                s += (int)(YP[d * 126 + t + 1] - YP[d * 126 + t]) * (int)XP[d * 126 + 125];
            R[t] = s;
        }
        __syncthreads();
        if (t == 0) {                               // row prefix (serial, 125)
            int s = 0;
            for (int iy = 0; iy < 125; ++iy) { RP[iy] = s; s += R[iy]; }
            RP[125] = s;
            if (b == 0) *E_global = s;
        }
        __syncthreads();

        int pt = b * 256 + t;                       // covers NPTS exactly
        int d = pt / HW, hw = pt - d * HW, h = hw / W, w = hw - h * W;
        float dep = (float)(d + 2);
        int X = ix_of(w, dep), Y = iy_of(h, dep);
        if (X > 124 || Y > 124) return;
        // pos = offset(bin) + rank-within-bin, all closed-form:
        int pos = RP[Y] + (w - (int)XP[d * 126 + X]);
        int xc_d = 0;
        for (int dd = 0; dd < D; ++dd) {
            int xp  = XP[dd * 126 + X];
            int xc_ = XP[dd * 126 + X + 1] - xp;
            int yc_ = YP[dd * 126 + Y + 1] - YP[dd * 126 + Y];
            pos += yc_ * xp;                        // bins (Y, X'<X)
            if (dd < d) pos += xc_ * yc_;           // earlier depths, same bin
            if (dd == d) xc_d = xc_;
        }
        pos += (h - (int)YP[d * 126 + Y]) * xc_d;
        int bin = Y * BEV + X;
        entries[pos] = ((unsigned)bin << 18) | ((unsigned)d << 12) | (unsigned)hw;

    } else if (b < FILL_BLOCKS + PACK_BLOCKS) {
        int b2 = b - FILL_BLOCKS;
        int c0  = (b2 / 88) * 8;
        int hw0 = (b2 % 88) * 32;
        float* tile = (float*)smem;                 // [6][8][37] = 7104 B
        int cq = t >> 5, hwL = t & 31;
#pragma unroll
        for (int n = 0; n < NCAM; ++n)
            tile[(n * 8 + cq) * 37 + hwL] =
                feat[((size_t)(n * C + c0 + cq)) * HW + hw0 + hwL];
        __syncthreads();
        int hl = t >> 3, cL = t & 7;
        us8 v;
#pragma unroll
        for (int n = 0; n < NCAM; ++n)
            v[n] = f2bf(tile[(n * 8 + cL) * 37 + hl]);
        v[6] = 0; v[7] = 0;
        *(us8*)(feat_p + ((size_t)(hw0 + hl) * C + (c0 + cL)) * 8) = v;

    } else if (b < FILL_BLOCKS + PACK_BLOCKS + SMAX_BLOCKS) {
        int col = (b - FILL_BLOCKS - PACK_BLOCKS) * 256 + t;
        int n  = col / HW;
        int hw = col - n * HW;
        const float* src = logits + ((size_t)n * D) * HW + hw;
        float v[D];
        float m = -3.402823466e+38f;
#pragma unroll
        for (int d = 0; d < D; ++d) {
            v[d] = src[(size_t)d * HW];
            m = fmaxf(m, v[d]);
        }
        float s = 0.f;
#pragma unroll
        for (int d = 0; d < D; ++d) { v[d] = expf(v[d] - m); s += v[d]; }
        float inv = 1.0f / s;
#pragma unroll
        for (int d = 0; d < D; ++d)
            probs_t[(size_t)((d << 12) | hw) * 8 + n] = v[d] * inv;

    } else {
        int base = (b - FILL_BLOCKS - PACK_BLOCKS - SMAX_BLOCKS) * 1024;
#pragma unroll
        for (int k = 0; k < 4; ++k) {
            int i = base + k * 256 + t;
            if (i < ZERO_TOTAL) ((f4*)out)[i] = f4{0.f, 0.f, 0.f, 0.f};
        }
    }
}

// ---------------------------------------------------------------- D2: gather
// chunk=32 entries, 128 thr (2 waves) = c. Entries preloaded with ONE
// coalesced load per wave, broadcast by shfl -> no per-iter load->addr chain.
// Batch-4: 12 loads in flight. Interior bins plain-store; boundary atomics.
constexpr int CHUNK  = 32;
constexpr int NCHUNK = NPTS / CHUNK;                 // 3520 (div by 8)

__global__ void __launch_bounds__(128) gather_kernel(
        const unsigned short* __restrict__ feat_p,   // [hw][c][8] bf16
        const float* __restrict__ probs_t,           // [(d<<12)|hw][8] f32
        const int*   __restrict__ entries,
        const int*   __restrict__ E_global,
        float*       __restrict__ out) {             // [C][NBINS], zeroed
    int E = *E_global;
    int b = blockIdx.x;
    int chunk = (b & 7) * (NCHUNK / 8) + (b >> 3);   // XCD-contiguous bins
    int e0 = chunk * CHUNK;
    if (e0 >= E) return;
    int m = min(CHUNK, E - e0);
    int c = threadIdx.x;
    int lane = threadIdx.x & 63;

    int myent = entries[e0 + (lane & 31)];           // 1 coalesced load
    unsigned prevbin = (e0 > 0) ? ((unsigned)entries[e0 - 1] >> 18) : 0xFFFFFFFFu;
    unsigned nextbin = (e0 + CHUNK < E) ? ((unsigned)entries[e0 + CHUNK] >> 18) : 0xFFFFFFFFu;

    float acc = 0.f;
    int curbin = -1;
    bool inside = true;

    for (int j0 = 0; j0 < m; j0 += 4) {
        int kk = min(4, m - j0);
        unsigned pk[4]; us8 fv[4]; f4 pa[4], pb[4];
#pragma unroll
        for (int k = 0; k < 4; ++k) if (k < kk) {
            pk[k] = (unsigned)__shfl(myent, j0 + k);
            fv[k] = *(const us8*)(feat_p + (((size_t)(pk[k] & 0xFFFu) << 7) + (unsigned)c) * 8);
            const float* pp = probs_t + ((size_t)(pk[k] & 0x3FFFFu) << 3);
            pa[k] = *(const f4*)pp;
            pb[k] = *(const f4*)(pp + 4);
        }
#pragma unroll
        for (int k = 0; k < 4; ++k) if (k < kk) {
            int bin = (int)(pk[k] >> 18);            // wave-uniform
            if (bin != curbin) {
                if (curbin >= 0) {
                    if (inside) out[(size_t)c * NBINS + curbin] = acc;
                    else        atomicAdd(&out[(size_t)c * NBINS + curbin], acc);
                }
                inside = !(curbin < 0 && (unsigned)bin == prevbin);
                curbin = bin; acc = 0.f;
            }
            acc += pa[k].x * b2f(fv[k][0]) + pa[k].y * b2f(fv[k][1])
                 + pa[k].z * b2f(fv[k][2]) + pa[k].w * b2f(fv[k][3])
                 + pb[k].x * b2f(fv[k][4]) + pb[k].y * b2f(fv[k][5]);
        }
    }
    if (!inside || (unsigned)curbin == nextbin)
        atomicAdd(&out[(size_t)c * NBINS + curbin], acc);
    else
        out[(size_t)c * NBINS + curbin] = acc;
}

// ---------------------------------------------------------------- launch
extern "C" void kernel_launch(void* const* d_in, const int* in_sizes, int n_in,
                              void* d_out, int out_size, void* d_ws, size_t ws_size,
                              hipStream_t stream) {
    const float* img_feat     = (const float*)d_in[0];
    const float* depth_logits = (const float*)d_in[1];
    float* out = (float*)d_out;

    char* p = (char*)d_ws;
    float*          probs_t = (float*)p;          p += (size_t)D * 4096 * 8 * 4;  // 5.24 MB
    unsigned short* feat_p  = (unsigned short*)p; p += (size_t)HW * C * 8 * 2;    // 5.77 MB
    int*            entries = (int*)p;            p += (size_t)NPTS * 4;          // 450 KB
    int*            E_global = (int*)p;           p += 16;

    mega_kernel<<<FILL_BLOCKS + PACK_BLOCKS + SMAX_BLOCKS + ZERO_BLOCKS, 256, 0, stream>>>(
        img_feat, depth_logits, probs_t, feat_p, entries, E_global, out);
    gather_kernel<<<NCHUNK, 128, 0, stream>>>(feat_p, probs_t, entries, E_global, out);
}